// Round 3
// baseline (877.180 us; speedup 1.0000x reference)
//
#include <hip/hip_runtime.h>

#define BB 64
#define NN 4096
#define MM 128
#define SCALE 0.25f
#define BGRP 8            // b's per block = waves per block
#define NR 64             // n-range per block
#define NC 2              // n rows per LDS chunk
#define CHUNKS (NR / NC)

typedef const __attribute__((address_space(1))) void* gp_t;
typedef __attribute__((address_space(3))) void* lp_t;

// Block: 8 waves, wave i owns b = bgrp*8+i. All waves share LDS-staged w rows.
// Lane l owns m = 2l, 2l+1. Votes live in regs for qk-dot and out-accum.
__global__ __launch_bounds__(512, 4) void caps_fused(const float* __restrict__ x,
                                                     const float* __restrict__ ncv,
                                                     const float* __restrict__ w,
                                                     float* __restrict__ out_acc) {
    const int bgrp   = blockIdx.x & 7;
    const int nsplit = blockIdx.x >> 3;
    const int wave   = threadIdx.x >> 6;
    const int lane   = threadIdx.x & 63;
    const int b      = bgrp * BGRP + wave;
    const int n0     = nsplit * NR;
    const int m0     = lane * 2;

    __shared__ float lds_w[2][NC * 2048];       // 2 x 16 KB
    __shared__ float lds_p[2][BGRP * NC * 16];  // 2 x 1 KB

    // ncv[b, m0, :], ncv[b, m0+1, :]
    float nc0[16], nc1[16];
    {
        const float4* p0 = (const float4*)(ncv + ((size_t)b * MM + m0) * 16);
        const float4* p1 = (const float4*)(ncv + ((size_t)b * MM + m0 + 1) * 16);
#pragma unroll
        for (int i = 0; i < 4; ++i) {
            float4 t = p0[i];
            nc0[4 * i + 0] = t.x; nc0[4 * i + 1] = t.y; nc0[4 * i + 2] = t.z; nc0[4 * i + 3] = t.w;
            float4 u = p1[i];
            nc1[4 * i + 0] = u.x; nc1[4 * i + 1] = u.y; nc1[4 * i + 2] = u.z; nc1[4 * i + 3] = u.w;
        }
    }

    float oa0[16], oa1[16];
#pragma unroll
    for (int k = 0; k < 16; ++k) { oa0[k] = 0.0f; oa1[k] = 0.0f; }

    auto stage = [&](int c, int buf) {
        // w rows n0+c*NC .. +NC-1 : NC*8KB contiguous, linear into LDS
        const float* wsrc = w + (size_t)(n0 + c * NC) * 2048;
#pragma unroll
        for (int j = 0; j < NC; ++j) {
            const int off = (wave * NC + j) * 256;   // floats
            __builtin_amdgcn_global_load_lds((gp_t)(wsrc + off + lane * 4),
                                             (lp_t)(&lds_w[buf][off]), 16, 0, 0);
        }
        // pose for all 8 b's of this chunk: lane -> b'=lane>>3, quad q=lane&7
        if (wave == 0) {
            const int bp = lane >> 3, q = lane & 7;
            const float* psrc = x + ((size_t)(bgrp * BGRP + bp) * NN + n0 + c * NC) * 16 + q * 4;
            __builtin_amdgcn_global_load_lds((gp_t)psrc, (lp_t)(&lds_p[buf][0]), 16, 0, 0);
        }
    };

    stage(0, 0);
    __syncthreads();

    for (int c = 0; c < CHUNKS; ++c) {
        const int buf = c & 1;
        if (c + 1 < CHUNKS) stage(c + 1, buf ^ 1);
#pragma unroll
        for (int nn = 0; nn < NC; ++nn) {
            const float* wrow = &lds_w[buf][nn * 2048 + m0];
            const float* pt   = &lds_p[buf][wave * (NC * 16) + nn * 16];
            // pose row (wave-uniform broadcast reads)
            float4 pA = *(const float4*)(pt + 0);
            float4 pB = *(const float4*)(pt + 4);
            float4 pC = *(const float4*)(pt + 8);
            float4 pD = *(const float4*)(pt + 12);
            // votes v[a*4+d] = sum_x pose[a][x] * w[x*4+d]
            float v0[16], v1[16];
#pragma unroll
            for (int d = 0; d < 4; ++d) {
                float2 w0 = *(const float2*)(wrow + (0 * 4 + d) * 128);
                float2 w1 = *(const float2*)(wrow + (1 * 4 + d) * 128);
                float2 w2 = *(const float2*)(wrow + (2 * 4 + d) * 128);
                float2 w3 = *(const float2*)(wrow + (3 * 4 + d) * 128);
                v0[0  + d] = fmaf(pA.x, w0.x, fmaf(pA.y, w1.x, fmaf(pA.z, w2.x, pA.w * w3.x)));
                v1[0  + d] = fmaf(pA.x, w0.y, fmaf(pA.y, w1.y, fmaf(pA.z, w2.y, pA.w * w3.y)));
                v0[4  + d] = fmaf(pB.x, w0.x, fmaf(pB.y, w1.x, fmaf(pB.z, w2.x, pB.w * w3.x)));
                v1[4  + d] = fmaf(pB.x, w0.y, fmaf(pB.y, w1.y, fmaf(pB.z, w2.y, pB.w * w3.y)));
                v0[8  + d] = fmaf(pC.x, w0.x, fmaf(pC.y, w1.x, fmaf(pC.z, w2.x, pC.w * w3.x)));
                v1[8  + d] = fmaf(pC.x, w0.y, fmaf(pC.y, w1.y, fmaf(pC.z, w2.y, pC.w * w3.y)));
                v0[12 + d] = fmaf(pD.x, w0.x, fmaf(pD.y, w1.x, fmaf(pD.z, w2.x, pD.w * w3.x)));
                v1[12 + d] = fmaf(pD.x, w0.y, fmaf(pD.y, w1.y, fmaf(pD.z, w2.y, pD.w * w3.y)));
            }
            // qk = SCALE * <v, nc>
            float qk0 = 0.0f, qk1 = 0.0f;
#pragma unroll
            for (int k = 0; k < 16; ++k) {
                qk0 = fmaf(v0[k], nc0[k], qk0);
                qk1 = fmaf(v1[k], nc1[k], qk1);
            }
            // softmax over 128 m (2/lane). |qk*SCALE| <~ 3 analytically -> no max
            // subtraction needed (exp(x)/sum(exp) is exact softmax).
            float p0 = __expf(qk0 * SCALE), p1 = __expf(qk1 * SCALE);
            float s = p0 + p1;
#pragma unroll
            for (int off = 32; off; off >>= 1) s += __shfl_xor(s, off);
            float rinv = 1.0f / s;
            float r0 = p0 * rinv, r1 = p1 * rinv;
#pragma unroll
            for (int k = 0; k < 16; ++k) {
                oa0[k] = fmaf(r0, v0[k], oa0[k]);
                oa1[k] = fmaf(r1, v1[k], oa1[k]);
            }
        }
        __syncthreads();
    }

    // Each wave owns a distinct b -> atomically fold its partial into acc[b].
    float* gout = out_acc + (size_t)b * (MM * 16);
#pragma unroll
    for (int k = 0; k < 16; ++k) {
        atomicAdd(gout + m0 * 16 + k, oa0[k]);
        atomicAdd(gout + (m0 + 1) * 16 + k, oa1[k]);
    }
}

// LayerNorm over last dim (16) of acc[b, m, 16] -> out
__global__ __launch_bounds__(256) void caps_ln(const float* __restrict__ acc,
                                               const float* __restrict__ gamma,
                                               const float* __restrict__ beta,
                                               float* __restrict__ out) {
    int r = blockIdx.x * blockDim.x + threadIdx.x;
    if (r >= BB * MM) return;
    float v[16];
    const float4* p = (const float4*)(acc + (size_t)r * 16);
#pragma unroll
    for (int i = 0; i < 4; ++i) {
        float4 t = p[i];
        v[4 * i + 0] = t.x; v[4 * i + 1] = t.y; v[4 * i + 2] = t.z; v[4 * i + 3] = t.w;
    }
    float mu = 0.0f;
#pragma unroll
    for (int k = 0; k < 16; ++k) mu += v[k];
    mu *= (1.0f / 16.0f);
    float var = 0.0f;
#pragma unroll
    for (int k = 0; k < 16; ++k) {
        float d = v[k] - mu;
        var = fmaf(d, d, var);
    }
    var *= (1.0f / 16.0f);
    float rs = rsqrtf(var + 1e-5f);
    float4* o = (float4*)(out + (size_t)r * 16);
#pragma unroll
    for (int i = 0; i < 4; ++i) {
        float4 t;
        t.x = (v[4 * i + 0] - mu) * rs * gamma[4 * i + 0] + beta[4 * i + 0];
        t.y = (v[4 * i + 1] - mu) * rs * gamma[4 * i + 1] + beta[4 * i + 1];
        t.z = (v[4 * i + 2] - mu) * rs * gamma[4 * i + 2] + beta[4 * i + 2];
        t.w = (v[4 * i + 3] - mu) * rs * gamma[4 * i + 3] + beta[4 * i + 3];
        o[i] = t;
    }
}

extern "C" void kernel_launch(void* const* d_in, const int* in_sizes, int n_in,
                              void* d_out, int out_size, void* d_ws, size_t ws_size,
                              hipStream_t stream) {
    const float* x     = (const float*)d_in[0];
    const float* ncv   = (const float*)d_in[1];
    const float* w     = (const float*)d_in[2];
    const float* gamma = (const float*)d_in[3];
    const float* beta  = (const float*)d_in[4];
    float* out = (float*)d_out;
    float* acc = (float*)d_ws;   // BB*MM*16 fp32 accumulator = 512 KiB

    hipMemsetAsync(acc, 0, (size_t)BB * MM * 16 * sizeof(float), stream);

    dim3 grid((BB / BGRP) * (NN / NR));   // 8 * 64 = 512 blocks, 2/CU
    caps_fused<<<grid, BGRP * 64, 0, stream>>>(x, ncv, w, acc);

    caps_ln<<<(BB * MM + 255) / 256, 256, 0, stream>>>(acc, gamma, beta, out);
}

// Round 4
// 666.589 us; speedup vs baseline: 1.3159x; 1.3159x over previous
//
#include <hip/hip_runtime.h>

#define BB 64
#define NN 4096
#define MM 128
#define SCALE 0.25f
#define BGRP 8            // b's per block = waves per block
#define NR 64             // n-range per block
#define NC 2              // n rows per LDS chunk
#define CHUNKS (NR / NC)

typedef const __attribute__((address_space(1))) void* gp_t;
typedef __attribute__((address_space(3))) void* lp_t;

// Block: 8 waves, wave i owns b = bgrp*8+i. All waves share LDS-staged w rows.
// Lane l owns m = 2l, 2l+1. Votes live in regs for qk-dot and out-accum.
// Epilogue: COALESCED atomics into acc[b][k][m] (m fastest) — consecutive
// lanes hit consecutive 4B addresses (R2-proven cheap pattern).
__global__ __launch_bounds__(512, 4) void caps_fused(const float* __restrict__ x,
                                                     const float* __restrict__ ncv,
                                                     const float* __restrict__ w,
                                                     float* __restrict__ out_acc) {
    const int bgrp   = blockIdx.x & 7;
    const int nsplit = blockIdx.x >> 3;
    const int wave   = threadIdx.x >> 6;
    const int lane   = threadIdx.x & 63;
    const int b      = bgrp * BGRP + wave;
    const int n0     = nsplit * NR;
    const int m0     = lane * 2;

    __shared__ float lds_w[2][NC * 2048];       // 2 x 16 KB
    __shared__ float lds_p[2][BGRP * NC * 16];  // 2 x 1 KB

    // ncv[b, m0, :], ncv[b, m0+1, :]
    float nc0[16], nc1[16];
    {
        const float4* p0 = (const float4*)(ncv + ((size_t)b * MM + m0) * 16);
        const float4* p1 = (const float4*)(ncv + ((size_t)b * MM + m0 + 1) * 16);
#pragma unroll
        for (int i = 0; i < 4; ++i) {
            float4 t = p0[i];
            nc0[4 * i + 0] = t.x; nc0[4 * i + 1] = t.y; nc0[4 * i + 2] = t.z; nc0[4 * i + 3] = t.w;
            float4 u = p1[i];
            nc1[4 * i + 0] = u.x; nc1[4 * i + 1] = u.y; nc1[4 * i + 2] = u.z; nc1[4 * i + 3] = u.w;
        }
    }

    float oa0[16], oa1[16];
#pragma unroll
    for (int k = 0; k < 16; ++k) { oa0[k] = 0.0f; oa1[k] = 0.0f; }

    auto stage = [&](int c, int buf) {
        // w rows n0+c*NC .. +NC-1 : NC*8KB contiguous, linear into LDS
        const float* wsrc = w + (size_t)(n0 + c * NC) * 2048;
#pragma unroll
        for (int j = 0; j < NC; ++j) {
            const int off = (wave * NC + j) * 256;   // floats
            __builtin_amdgcn_global_load_lds((gp_t)(wsrc + off + lane * 4),
                                             (lp_t)(&lds_w[buf][off]), 16, 0, 0);
        }
        // pose for all 8 b's of this chunk: lane -> b'=lane>>3, quad q=lane&7
        // (q=0..7 spans NC=2 consecutive 16-float rows, contiguous in x)
        if (wave == 0) {
            const int bp = lane >> 3, q = lane & 7;
            const float* psrc = x + ((size_t)(bgrp * BGRP + bp) * NN + n0 + c * NC) * 16 + q * 4;
            __builtin_amdgcn_global_load_lds((gp_t)psrc, (lp_t)(&lds_p[buf][0]), 16, 0, 0);
        }
    };

    stage(0, 0);
    __syncthreads();

    for (int c = 0; c < CHUNKS; ++c) {
        const int buf = c & 1;
        if (c + 1 < CHUNKS) stage(c + 1, buf ^ 1);
#pragma unroll
        for (int nn = 0; nn < NC; ++nn) {
            const float* wrow = &lds_w[buf][nn * 2048 + m0];
            const float* pt   = &lds_p[buf][wave * (NC * 16) + nn * 16];
            // pose row (wave-uniform broadcast reads)
            float4 pA = *(const float4*)(pt + 0);
            float4 pB = *(const float4*)(pt + 4);
            float4 pC = *(const float4*)(pt + 8);
            float4 pD = *(const float4*)(pt + 12);
            // votes v[a*4+d] = sum_x pose[a][x] * w[x*4+d]
            float v0[16], v1[16];
#pragma unroll
            for (int d = 0; d < 4; ++d) {
                float2 w0 = *(const float2*)(wrow + (0 * 4 + d) * 128);
                float2 w1 = *(const float2*)(wrow + (1 * 4 + d) * 128);
                float2 w2 = *(const float2*)(wrow + (2 * 4 + d) * 128);
                float2 w3 = *(const float2*)(wrow + (3 * 4 + d) * 128);
                v0[0  + d] = fmaf(pA.x, w0.x, fmaf(pA.y, w1.x, fmaf(pA.z, w2.x, pA.w * w3.x)));
                v1[0  + d] = fmaf(pA.x, w0.y, fmaf(pA.y, w1.y, fmaf(pA.z, w2.y, pA.w * w3.y)));
                v0[4  + d] = fmaf(pB.x, w0.x, fmaf(pB.y, w1.x, fmaf(pB.z, w2.x, pB.w * w3.x)));
                v1[4  + d] = fmaf(pB.x, w0.y, fmaf(pB.y, w1.y, fmaf(pB.z, w2.y, pB.w * w3.y)));
                v0[8  + d] = fmaf(pC.x, w0.x, fmaf(pC.y, w1.x, fmaf(pC.z, w2.x, pC.w * w3.x)));
                v1[8  + d] = fmaf(pC.x, w0.y, fmaf(pC.y, w1.y, fmaf(pC.z, w2.y, pC.w * w3.y)));
                v0[12 + d] = fmaf(pD.x, w0.x, fmaf(pD.y, w1.x, fmaf(pD.z, w2.x, pD.w * w3.x)));
                v1[12 + d] = fmaf(pD.x, w0.y, fmaf(pD.y, w1.y, fmaf(pD.z, w2.y, pD.w * w3.y)));
            }
            // qk = SCALE * <v, nc>
            float qk0 = 0.0f, qk1 = 0.0f;
#pragma unroll
            for (int k = 0; k < 16; ++k) {
                qk0 = fmaf(v0[k], nc0[k], qk0);
                qk1 = fmaf(v1[k], nc1[k], qk1);
            }
            // softmax over 128 m (2/lane). |qk*SCALE| <~ 1 analytically -> no
            // max subtraction needed (exp(x)/sum(exp) is exact softmax).
            float p0 = __expf(qk0 * SCALE), p1 = __expf(qk1 * SCALE);
            float s = p0 + p1;
#pragma unroll
            for (int off = 32; off; off >>= 1) s += __shfl_xor(s, off);
            float rinv = 1.0f / s;
            float r0 = p0 * rinv, r1 = p1 * rinv;
#pragma unroll
            for (int k = 0; k < 16; ++k) {
                oa0[k] = fmaf(r0, v0[k], oa0[k]);
                oa1[k] = fmaf(r1, v1[k], oa1[k]);
            }
        }
        __syncthreads();
    }

    // Coalesced atomic fold into acc[b][k][m]: for each k the wave writes one
    // contiguous 512B span (consecutive lanes -> consecutive 4B addresses).
    float* gout = out_acc + (size_t)b * (16 * MM);
#pragma unroll
    for (int k = 0; k < 16; ++k) {
        atomicAdd(gout + k * MM + m0,     oa0[k]);
        atomicAdd(gout + k * MM + m0 + 1, oa1[k]);
    }
}

// Block per b. acc[b][k][m] -> LDS -> thread-per-m LayerNorm -> out[b][m][k].
__global__ __launch_bounds__(128) void caps_ln(const float* __restrict__ acc,
                                               const float* __restrict__ gamma,
                                               const float* __restrict__ beta,
                                               float* __restrict__ out) {
    const int b = blockIdx.x;
    const int t = threadIdx.x;   // = m
    __shared__ float lds[16 * MM];
    const float* gacc = acc + (size_t)b * (16 * MM);
#pragma unroll
    for (int j = 0; j < 4; ++j) {
        const int idx = j * 512 + t * 4;
        *(float4*)(lds + idx) = *(const float4*)(gacc + idx);   // coalesced
    }
    __syncthreads();
    float v[16];
    float mu = 0.0f;
#pragma unroll
    for (int k = 0; k < 16; ++k) { v[k] = lds[k * MM + t]; mu += v[k]; }  // 2 lanes/bank: free
    mu *= (1.0f / 16.0f);
    float var = 0.0f;
#pragma unroll
    for (int k = 0; k < 16; ++k) { float d = v[k] - mu; var = fmaf(d, d, var); }
    var *= (1.0f / 16.0f);
    float rs = rsqrtf(var + 1e-5f);
    float4* o = (float4*)(out + ((size_t)b * MM + t) * 16);
#pragma unroll
    for (int i = 0; i < 4; ++i) {
        float4 r;
        r.x = (v[4 * i + 0] - mu) * rs * gamma[4 * i + 0] + beta[4 * i + 0];
        r.y = (v[4 * i + 1] - mu) * rs * gamma[4 * i + 1] + beta[4 * i + 1];
        r.z = (v[4 * i + 2] - mu) * rs * gamma[4 * i + 2] + beta[4 * i + 2];
        r.w = (v[4 * i + 3] - mu) * rs * gamma[4 * i + 3] + beta[4 * i + 3];
        o[i] = r;
    }
}

extern "C" void kernel_launch(void* const* d_in, const int* in_sizes, int n_in,
                              void* d_out, int out_size, void* d_ws, size_t ws_size,
                              hipStream_t stream) {
    const float* x     = (const float*)d_in[0];
    const float* ncv   = (const float*)d_in[1];
    const float* w     = (const float*)d_in[2];
    const float* gamma = (const float*)d_in[3];
    const float* beta  = (const float*)d_in[4];
    float* out = (float*)d_out;
    float* acc = (float*)d_ws;   // BB*16*MM fp32 accumulator = 512 KiB, [b][k][m]

    hipMemsetAsync(acc, 0, (size_t)BB * 16 * MM * sizeof(float), stream);

    dim3 grid((BB / BGRP) * (NN / NR));   // 8 * 64 = 512 blocks, 2/CU
    caps_fused<<<grid, BGRP * 64, 0, stream>>>(x, ncv, w, acc);

    caps_ln<<<BB, 128, 0, stream>>>(acc, gamma, beta, out);
}